// Round 1
// baseline (302.996 us; speedup 1.0000x reference)
//
#include <hip/hip_runtime.h>
#include <math.h>

// ---------------- problem constants ----------------
constexpr float C_CURV = 0.1f;
constexpr float SQRT_C = 0.31622776601683794f;        // sqrt(0.1)
constexpr float TWO_OVER_SQRT_C = 6.324555320336759f; // 2/sqrt(0.1)

constexpr int N_GENUS   = 60;
constexpr int N_SPECIES = 4096;
constexpr int NB        = 1024;   // batch
constexpr int EMB       = 64;

// ---------------- workspace layout (floats) ----------------
constexpr int OFF_HYP_S = 0;                               // 4096*64
constexpr int OFF_HYP_G = OFF_HYP_S + N_SPECIES * EMB;     // 60*64
constexpr int OFF_S2    = OFF_HYP_G + N_GENUS * EMB;       // 4096
constexpr int OFF_G2    = OFF_S2 + N_SPECIES;              // 64 (60 used)
constexpr int OFF_X2    = OFF_G2 + 64;                     // 1024
constexpr int OFF_PRES  = OFF_X2 + NB;                     // 4096
constexpr int OFF_ACC   = OFF_PRES + N_SPECIES;            // 8: [0]=pos_sp [1]=neg_sp [2]=pos_g [3]=neg_g [4]=nvs [5]=nvg

// ---------------- helpers ----------------
__device__ __forceinline__ float wave_sum(float v) {
    #pragma unroll
    for (int off = 32; off; off >>= 1) v += __shfl_xor(v, off);
    return v;
}

// dist = 2/sqrt(c) * atanh(clip(sqrt(c)*||(-x) mobius+ y|| / |denom|, 0, 1-1e-5))
// expanded: ||num||^2 = ca^2*a2 + 2*ca*cy*dot + cy^2*y2  (dot = a.y, a = -x)
__device__ __forceinline__ float hyp_dist(float dot_ay, float a2, float y2) {
    float ca   = 1.0f + 2.0f * C_CURV * dot_ay + C_CURV * y2;
    float cy   = 1.0f - C_CURV * a2;
    float num2 = ca * ca * a2 + 2.0f * ca * cy * dot_ay + cy * cy * y2;
    float den  = 1.0f + 2.0f * C_CURV * dot_ay + C_CURV * C_CURV * a2 * y2;
    float madd = sqrtf(fmaxf(num2, 0.0f)) / fmaxf(fabsf(den), 1e-15f);
    float arg  = fminf(SQRT_C * madd, 1.0f - 1e-5f);
    return TWO_OVER_SQRT_C * atanhf(arg);
}

// ---------------- K1: project rows onto Poincare ball + norms^2 ----------------
// wave w: w < 4096 -> species row; < 4156 -> genus row; < 5180 -> X row (norm^2 only)
__global__ __launch_bounds__(256) void k_project(
    const float* __restrict__ X, const float* __restrict__ gp,
    const float* __restrict__ sp, float* __restrict__ ws)
{
    int wave = (blockIdx.x * blockDim.x + threadIdx.x) >> 6;
    int lane = threadIdx.x & 63;
    if (wave >= N_SPECIES + N_GENUS + NB) return;

    float v;
    if (wave < N_SPECIES)            v = sp[wave * EMB + lane];
    else if (wave < N_SPECIES + N_GENUS) v = gp[(wave - N_SPECIES) * EMB + lane];
    else                             v = X[(wave - N_SPECIES - N_GENUS) * EMB + lane];

    float ss = wave_sum(v * v);
    if (wave >= N_SPECIES + N_GENUS) {          // X rows: just ||x||^2
        if (lane == 0) ws[OFF_X2 + (wave - N_SPECIES - N_GENUS)] = ss;
        return;
    }

    // feature clip
    float n  = fmaxf(sqrtf(ss), 1e-5f);
    v *= fminf(1.0f, 2.3f / n);
    float n2 = fminf(n, 2.3f);                  // == max(||clipped||,1e-5) exactly
    // expmap0
    float fac = tanhf(SQRT_C * n2) / (SQRT_C * n2);
    float y = fac * v;
    // project inside ball
    float ss2 = wave_sum(y * y);
    float yn = fmaxf(sqrtf(ss2), 1e-5f);
    const float maxnorm = (1.0f - 1e-3f) / SQRT_C;
    if (yn > maxnorm) {                         // wave-uniform branch
        y *= maxnorm / yn;
        ss2 = wave_sum(y * y);
    }
    if (wave < N_SPECIES) {
        ws[OFF_HYP_S + wave * EMB + lane] = y;
        if (lane == 0) ws[OFF_S2 + wave] = ss2;
    } else {
        int g = wave - N_SPECIES;
        ws[OFF_HYP_G + g * EMB + lane] = y;
        if (lane == 0) ws[OFF_G2 + g] = ss2;
    }
}

// ---------------- K2: present mask, nvs, nvg (single block) ----------------
__global__ __launch_bounds__(1024) void k_masks(
    const int* __restrict__ Ts, const int* __restrict__ s2g, float* __restrict__ ws)
{
    __shared__ unsigned char pres[N_SPECIES];
    __shared__ unsigned char gm[64];
    __shared__ int cnt[2];
    int t = threadIdx.x;
    for (int s = t; s < N_SPECIES; s += 1024) pres[s] = 0;
    if (t < 64) gm[t] = 0;
    if (t < 2)  cnt[t] = 0;
    __syncthreads();
    pres[Ts[t]] = 1;                 // t in [0,1024)
    __syncthreads();
    int local = 0;
    for (int s = t; s < N_SPECIES; s += 1024) {
        unsigned char p = pres[s];
        ws[OFF_PRES + s] = (float)p;
        if (p) { gm[s2g[s]] = 1; local++; }
    }
    if (local) atomicAdd(&cnt[0], local);
    __syncthreads();
    if (t < N_GENUS && gm[t]) atomicAdd(&cnt[1], 1);
    __syncthreads();
    if (t == 0) { ws[OFF_ACC + 4] = (float)cnt[0]; ws[OFF_ACC + 5] = (float)cnt[1]; }
}

// ---------------- K3: species-level pair distances (B x S) ----------------
// grid (64, 16): blockIdx.x -> 64-col species tile, blockIdx.y -> 64-row batch tile.
// 256 threads, 4x4 micro-tile, strided cols/rows (sx+16j, sy+16i) for bank-friendly reads.
#define LDPAD 68   // 17 float4s: keeps rows 16B-aligned, stride 68%32=4 banks apart
__global__ __launch_bounds__(256) void k_species_dist(
    const float* __restrict__ X, const int* __restrict__ Ts, float* __restrict__ ws)
{
    __shared__ float xs[64][LDPAD];
    __shared__ float ssm[64][LDPAD];
    __shared__ float x2s[64], s2s[64];
    __shared__ int   tss[64];

    int t = threadIdx.x;
    int sBase = blockIdx.x * 64;
    int bBase = blockIdx.y * 64;

    #pragma unroll
    for (int r = 0; r < 16; ++r) {
        int flat = r * 256 + t;          // 0..4095
        int row = flat >> 6, k = flat & 63;
        xs[row][k]  = X[(bBase + row) * EMB + k];
        ssm[row][k] = ws[OFF_HYP_S + (sBase + row) * EMB + k];
    }
    if (t < 64) {
        x2s[t] = ws[OFF_X2 + bBase + t];
        s2s[t] = ws[OFF_S2 + sBase + t];
        tss[t] = Ts[bBase + t];
    }
    __syncthreads();

    int sx = t & 15, sy = t >> 4;        // sy in [0,16) across 4 waves
    float acc[4][4];
    #pragma unroll
    for (int i = 0; i < 4; ++i)
        #pragma unroll
        for (int j = 0; j < 4; ++j) acc[i][j] = 0.0f;

    for (int k = 0; k < EMB; k += 4) {
        float4 av[4], bv[4];
        #pragma unroll
        for (int i = 0; i < 4; ++i)
            av[i] = *reinterpret_cast<const float4*>(&xs[sy + 16 * i][k]);
        #pragma unroll
        for (int j = 0; j < 4; ++j)
            bv[j] = *reinterpret_cast<const float4*>(&ssm[sx + 16 * j][k]);
        #pragma unroll
        for (int i = 0; i < 4; ++i)
            #pragma unroll
            for (int j = 0; j < 4; ++j)
                acc[i][j] += av[i].x * bv[j].x + av[i].y * bv[j].y
                           + av[i].z * bv[j].z + av[i].w * bv[j].w;
    }

    float pos = 0.0f, neg = 0.0f;
    #pragma unroll
    for (int i = 0; i < 4; ++i) {
        int bl = sy + 16 * i;
        float a2 = x2s[bl];
        int target = tss[bl];
        #pragma unroll
        for (int j = 0; j < 4; ++j) {
            int sl = sx + 16 * j;
            float d = hyp_dist(-acc[i][j], a2, s2s[sl]);   // d >= 0
            float l = log1pf(expf(-d));                    // softplus(-d)
            if (target == sBase + sl) pos += d + l;        // softplus(d)
            else                      neg += l;
        }
    }
    pos = wave_sum(pos);
    neg = wave_sum(neg);
    if ((t & 63) == 0) {
        atomicAdd(&ws[OFF_ACC + 0], pos);
        atomicAdd(&ws[OFF_ACC + 1], neg);
    }
}

// ---------------- K4: genus-level distances (present species only) ----------------
// 1024 blocks x 256 threads: each block = 4 species rows; thread t: s_local=t>>6, g=t&63
__global__ __launch_bounds__(256) void k_genus_dist(
    const int* __restrict__ s2g, float* __restrict__ ws)
{
    __shared__ float hgt[64][61];    // transposed genus tile [k][g], stride 61 (odd)
    __shared__ float hs[4][64];
    __shared__ float g2s[64];

    int t = threadIdx.x;
    int sBase = blockIdx.x * 4;

    for (int idx = t; idx < N_GENUS * EMB; idx += 256) {
        int g = idx >> 6, k = idx & 63;
        hgt[k][g] = ws[OFF_HYP_G + idx];
    }
    if (t < 64) g2s[t] = (t < N_GENUS) ? ws[OFF_G2 + t] : 0.0f;
    {
        int r = t >> 6, k = t & 63;
        hs[r][k] = ws[OFF_HYP_S + (sBase + r) * EMB + k];
    }
    __syncthreads();

    int s_l = t >> 6, g = t & 63;
    int s = sBase + s_l;
    float pos = 0.0f, neg = 0.0f;
    if (ws[OFF_PRES + s] > 0.5f) {   // wave-uniform
        if (g < N_GENUS) {
            float dot = 0.0f;
            #pragma unroll
            for (int k = 0; k < EMB; ++k) dot += hs[s_l][k] * hgt[k][g];
            float d = hyp_dist(-dot, ws[OFF_S2 + s], g2s[g]);
            float l = log1pf(expf(-d));
            if (s2g[s] == g) pos = d + l;
            else             neg = l;
        }
    }
    pos = wave_sum(pos);
    neg = wave_sum(neg);
    if ((t & 63) == 0) {
        atomicAdd(&ws[OFF_ACC + 2], pos);
        atomicAdd(&ws[OFF_ACC + 3], neg);
    }
}

// ---------------- K5: combine ----------------
__global__ void k_final(const float* __restrict__ ws, float* __restrict__ out)
{
    if (threadIdx.x == 0) {
        float nvs = fmaxf(ws[OFF_ACC + 4], 1.0f);
        float nvg = fmaxf(ws[OFF_ACC + 5], 1.0f);
        out[0] = ws[OFF_ACC + 0] / nvs + ws[OFF_ACC + 1] / (float)N_SPECIES
               + ws[OFF_ACC + 2] / nvg + ws[OFF_ACC + 3] / (float)N_GENUS;
    }
}

extern "C" void kernel_launch(void* const* d_in, const int* in_sizes, int n_in,
                              void* d_out, int out_size, void* d_ws, size_t ws_size,
                              hipStream_t stream) {
    const float* X   = (const float*)d_in[0];
    const int*   Ts  = (const int*)d_in[1];
    // d_in[2] = T_genus: unused by the reference loss
    const int*   s2g = (const int*)d_in[3];
    const float* gp  = (const float*)d_in[4];
    const float* sp  = (const float*)d_in[5];
    float* ws  = (float*)d_ws;
    float* out = (float*)d_out;

    // zero the atomic accumulators (ws is poisoned 0xAA before every call)
    hipMemsetAsync((char*)d_ws + OFF_ACC * sizeof(float), 0, 8 * sizeof(float), stream);

    // K1: (4096+60+1024) waves, 4 waves/block
    k_project<<<(N_SPECIES + N_GENUS + NB) / 4, 256, 0, stream>>>(X, gp, sp, ws);
    k_masks<<<1, 1024, 0, stream>>>(Ts, s2g, ws);
    dim3 g3(N_SPECIES / 64, NB / 64);   // (64, 16)
    k_species_dist<<<g3, 256, 0, stream>>>(X, Ts, ws);
    k_genus_dist<<<N_SPECIES / 4, 256, 0, stream>>>(s2g, ws);
    k_final<<<1, 64, 0, stream>>>(ws, out);
}

// Round 2
// 210.781 us; speedup vs baseline: 1.4375x; 1.4375x over previous
//
#include <hip/hip_runtime.h>
#include <math.h>

// ---------------- problem constants ----------------
constexpr float C_CURV = 0.1f;
constexpr float SQRT_C = 0.31622776601683794f;        // sqrt(0.1)

constexpr int N_GENUS   = 60;
constexpr int N_SPECIES = 4096;
constexpr int NB        = 1024;   // batch
constexpr int EMB       = 64;

// ---------------- workspace layout (floats) ----------------
constexpr int OFF_HYP_S = 0;                               // 4096*64
constexpr int OFF_HYP_G = OFF_HYP_S + N_SPECIES * EMB;     // 60*64
constexpr int OFF_S2    = OFF_HYP_G + N_GENUS * EMB;       // 4096
constexpr int OFF_G2    = OFF_S2 + N_SPECIES;              // 64 (60 used)
constexpr int OFF_X2    = OFF_G2 + 64;                     // 1024
constexpr int OFF_ACC   = OFF_X2 + NB;                     // 8 slots:
// [0]=pos_sp [1]=neg_sp [2]=pos_g [3]=neg_g [5]=nvg(float) [6]=count(int)
constexpr int OFF_LIST  = OFF_ACC + 8;                     // 1024 ints (compact present list)

// ---------------- helpers ----------------
__device__ __forceinline__ float wave_sum(float v) {
    #pragma unroll
    for (int off = 32; off; off >>= 1) v += __shfl_xor(v, off);
    return v;
}

// Given dot_ay = a.y (a = -x), a2 = ||a||^2, y2 = ||y||^2:
//   d      = 2/sqrt(c) * atanh(arg),  arg = clip(sqrt(c)*||num||/|den|, 0, 1-1e-5)
//   sp_neg = softplus(-d)
// Trick: u = (1-arg)/(1+arg) in (0,1];  L = log2(u)
//   d = -(ln2/sqrt(c)) * L,   exp(-d) = u^(1/sqrt(c)) = exp2(L/sqrt(c))
// All transcendentals native HW ops (v_sqrt/v_rcp/v_log/v_exp) — tolerance is ~2%.
__device__ __forceinline__ void pair_terms(float dot_ay, float a2, float y2,
                                           float& d, float& sp_neg) {
    float ca   = fmaf(2.0f * C_CURV, dot_ay, fmaf(C_CURV, y2, 1.0f));
    float cy   = fmaf(-C_CURV, a2, 1.0f);
    float num2 = fmaf(ca * ca, a2, fmaf(2.0f * ca * cy, dot_ay, cy * cy * y2));
    float den  = fmaf(2.0f * C_CURV, dot_ay, fmaf(C_CURV * C_CURV, a2 * y2, 1.0f));
    float arg  = SQRT_C * __builtin_amdgcn_sqrtf(fmaxf(num2, 0.0f))
                        * __builtin_amdgcn_rcpf(fmaxf(fabsf(den), 1e-15f));
    arg = fminf(arg, 1.0f - 1e-5f);
    float u = (1.0f - arg) * __builtin_amdgcn_rcpf(1.0f + arg);
    float L = __builtin_amdgcn_logf(u);                    // log2(u) <= 0
    d       = -2.19201176f * L;                            // (ln2/sqrt(c)) * (-L)
    float e = __builtin_amdgcn_exp2f(3.16227766f * L);     // exp(-d)
    sp_neg  = 0.69314718f * __builtin_amdgcn_logf(1.0f + e);
}

// ---------------- K1: project rows onto Poincare ball + norms^2 ----------------
__global__ __launch_bounds__(256) void k_project(
    const float* __restrict__ X, const float* __restrict__ gp,
    const float* __restrict__ sp, float* __restrict__ ws)
{
    int wave = (blockIdx.x * blockDim.x + threadIdx.x) >> 6;
    int lane = threadIdx.x & 63;
    if (wave >= N_SPECIES + N_GENUS + NB) return;

    float v;
    if (wave < N_SPECIES)                 v = sp[wave * EMB + lane];
    else if (wave < N_SPECIES + N_GENUS)  v = gp[(wave - N_SPECIES) * EMB + lane];
    else                                  v = X[(wave - N_SPECIES - N_GENUS) * EMB + lane];

    float ss = wave_sum(v * v);
    if (wave >= N_SPECIES + N_GENUS) {          // X rows: just ||x||^2
        if (lane == 0) ws[OFF_X2 + (wave - N_SPECIES - N_GENUS)] = ss;
        return;
    }

    float n  = fmaxf(sqrtf(ss), 1e-5f);
    v *= fminf(1.0f, 2.3f / n);
    float n2 = fminf(n, 2.3f);
    float fac = tanhf(SQRT_C * n2) / (SQRT_C * n2);
    float y = fac * v;
    float ss2 = wave_sum(y * y);
    float yn = fmaxf(sqrtf(ss2), 1e-5f);
    const float maxnorm = (1.0f - 1e-3f) / SQRT_C;
    if (yn > maxnorm) {                         // wave-uniform branch
        y *= maxnorm / yn;
        ss2 = wave_sum(y * y);
    }
    if (wave < N_SPECIES) {
        ws[OFF_HYP_S + wave * EMB + lane] = y;
        if (lane == 0) ws[OFF_S2 + wave] = ss2;
    } else {
        int g = wave - N_SPECIES;
        ws[OFF_HYP_G + g * EMB + lane] = y;
        if (lane == 0) ws[OFF_G2 + g] = ss2;
    }
}

// ---------------- K2: present mask -> compact list, nvs, nvg ----------------
__global__ __launch_bounds__(1024) void k_masks(
    const int* __restrict__ Ts, const int* __restrict__ s2g, float* __restrict__ ws)
{
    __shared__ unsigned char pres[N_SPECIES];
    __shared__ unsigned char gm[64];
    __shared__ int gcnt;
    int t = threadIdx.x;
    int* wsI = (int*)ws;
    for (int s = t; s < N_SPECIES; s += 1024) pres[s] = 0;
    if (t < 64) gm[t] = 0;
    if (t == 0) gcnt = 0;
    __syncthreads();
    pres[Ts[t]] = 1;                 // t in [0,1024)
    __syncthreads();
    for (int s = t; s < N_SPECIES; s += 1024) {
        if (pres[s]) {
            gm[s2g[s]] = 1;
            int idx = atomicAdd(&wsI[OFF_ACC + 6], 1);   // zeroed by memset
            wsI[OFF_LIST + idx] = s;
        }
    }
    __syncthreads();
    if (t < N_GENUS && gm[t]) atomicAdd(&gcnt, 1);
    __syncthreads();
    if (t == 0) ws[OFF_ACC + 5] = (float)gcnt;
}

// ---------------- K3: species-level pair distances (B x S) ----------------
#define LDPAD 68   // 17 float4s: rows 16B-aligned, row stride = 4 banks
__global__ __launch_bounds__(256) void k_species_dist(
    const float* __restrict__ X, const int* __restrict__ Ts, float* __restrict__ ws)
{
    __shared__ float xs[64][LDPAD];
    __shared__ float ssm[64][LDPAD];
    __shared__ float x2s[64], s2s[64];
    __shared__ int   tss[64];

    int t = threadIdx.x;
    int sBase = blockIdx.x * 64;
    int bBase = blockIdx.y * 64;

    #pragma unroll
    for (int r = 0; r < 16; ++r) {
        int flat = r * 256 + t;          // 0..4095
        int row = flat >> 6, k = flat & 63;
        xs[row][k]  = X[(bBase + row) * EMB + k];
        ssm[row][k] = ws[OFF_HYP_S + (sBase + row) * EMB + k];
    }
    if (t < 64) {
        x2s[t] = ws[OFF_X2 + bBase + t];
        s2s[t] = ws[OFF_S2 + sBase + t];
        tss[t] = Ts[bBase + t];
    }
    __syncthreads();

    int sx = t & 15, sy = t >> 4;
    float acc[4][4];
    #pragma unroll
    for (int i = 0; i < 4; ++i)
        #pragma unroll
        for (int j = 0; j < 4; ++j) acc[i][j] = 0.0f;

    #pragma unroll
    for (int k = 0; k < EMB; k += 4) {
        float4 av[4], bv[4];
        #pragma unroll
        for (int i = 0; i < 4; ++i)
            av[i] = *reinterpret_cast<const float4*>(&xs[sy + 16 * i][k]);
        #pragma unroll
        for (int j = 0; j < 4; ++j)
            bv[j] = *reinterpret_cast<const float4*>(&ssm[sx + 16 * j][k]);
        #pragma unroll
        for (int i = 0; i < 4; ++i)
            #pragma unroll
            for (int j = 0; j < 4; ++j)
                acc[i][j] = fmaf(av[i].x, bv[j].x, fmaf(av[i].y, bv[j].y,
                            fmaf(av[i].z, bv[j].z, fmaf(av[i].w, bv[j].w, acc[i][j]))));
    }

    float pos = 0.0f, neg = 0.0f;
    #pragma unroll
    for (int i = 0; i < 4; ++i) {
        int bl = sy + 16 * i;
        float a2 = x2s[bl];
        int target = tss[bl];
        #pragma unroll
        for (int j = 0; j < 4; ++j) {
            int sl = sx + 16 * j;
            float d, l;
            pair_terms(-acc[i][j], a2, s2s[sl], d, l);
            if (target == sBase + sl) pos += d + l;        // softplus(d) = d + softplus(-d)
            else                      neg += l;
        }
    }
    pos = wave_sum(pos);
    neg = wave_sum(neg);
    if ((t & 63) == 0) {
        atomicAdd(&ws[OFF_ACC + 0], pos);
        atomicAdd(&ws[OFF_ACC + 1], neg);
    }
}

// ---------------- K4: genus-level distances, compacted present species ----------------
// 256 blocks x 256 threads; wave w of block b handles present-list item b*4+w.
__global__ __launch_bounds__(256) void k_genus_dist(
    const int* __restrict__ s2g, float* __restrict__ ws)
{
    __shared__ float hgt[EMB][61];   // transposed genus tile [k][g], odd stride
    __shared__ float hs[4][EMB];
    __shared__ float g2s[64];

    int t = threadIdx.x;
    const int* wsI = (const int*)ws;
    int cnt  = wsI[OFF_ACC + 6];
    int w    = t >> 6, lane = t & 63;
    int item = blockIdx.x * 4 + w;
    int s    = (item < cnt) ? wsI[OFF_LIST + item] : -1;

    for (int idx = t; idx < N_GENUS * EMB; idx += 256)
        hgt[idx & 63][idx >> 6] = ws[OFF_HYP_G + idx];
    if (t < 64) g2s[t] = (t < N_GENUS) ? ws[OFF_G2 + t] : 0.0f;
    if (s >= 0) hs[w][lane] = ws[OFF_HYP_S + s * EMB + lane];
    __syncthreads();

    float pos = 0.0f, neg = 0.0f;
    if (s >= 0 && lane < N_GENUS) {
        float dot = 0.0f;
        #pragma unroll
        for (int k = 0; k < EMB; ++k) dot = fmaf(hs[w][k], hgt[k][lane], dot);
        float d, l;
        pair_terms(-dot, ws[OFF_S2 + s], g2s[lane], d, l);
        if (s2g[s] == lane) pos = d + l;
        else                neg = l;
    }
    pos = wave_sum(pos);
    neg = wave_sum(neg);
    if (lane == 0 && s >= 0) {
        atomicAdd(&ws[OFF_ACC + 2], pos);
        atomicAdd(&ws[OFF_ACC + 3], neg);
    }
}

// ---------------- K5: combine ----------------
__global__ void k_final(const float* __restrict__ ws, float* __restrict__ out)
{
    if (threadIdx.x == 0) {
        const int* wsI = (const int*)ws;
        float nvs = fmaxf((float)wsI[OFF_ACC + 6], 1.0f);
        float nvg = fmaxf(ws[OFF_ACC + 5], 1.0f);
        out[0] = ws[OFF_ACC + 0] / nvs + ws[OFF_ACC + 1] / (float)N_SPECIES
               + ws[OFF_ACC + 2] / nvg + ws[OFF_ACC + 3] / (float)N_GENUS;
    }
}

extern "C" void kernel_launch(void* const* d_in, const int* in_sizes, int n_in,
                              void* d_out, int out_size, void* d_ws, size_t ws_size,
                              hipStream_t stream) {
    const float* X   = (const float*)d_in[0];
    const int*   Ts  = (const int*)d_in[1];
    // d_in[2] = T_genus: unused by the reference loss
    const int*   s2g = (const int*)d_in[3];
    const float* gp  = (const float*)d_in[4];
    const float* sp  = (const float*)d_in[5];
    float* ws  = (float*)d_ws;
    float* out = (float*)d_out;

    hipMemsetAsync((char*)d_ws + OFF_ACC * sizeof(float), 0, 8 * sizeof(float), stream);

    k_project<<<(N_SPECIES + N_GENUS + NB) / 4, 256, 0, stream>>>(X, gp, sp, ws);
    k_masks<<<1, 1024, 0, stream>>>(Ts, s2g, ws);
    dim3 g3(N_SPECIES / 64, NB / 64);   // (64, 16)
    k_species_dist<<<g3, 256, 0, stream>>>(X, Ts, ws);
    k_genus_dist<<<256, 256, 0, stream>>>(s2g, ws);
    k_final<<<1, 64, 0, stream>>>(ws, out);
}

// Round 3
// 92.706 us; speedup vs baseline: 3.2684x; 2.2737x over previous
//
#include <hip/hip_runtime.h>
#include <math.h>

// ---------------- problem constants ----------------
constexpr float C_CURV = 0.1f;
constexpr float SQRT_C = 0.31622776601683794f;        // sqrt(0.1)

constexpr int N_GENUS   = 60;
constexpr int N_SPECIES = 4096;
constexpr int NB        = 1024;   // batch
constexpr int EMB       = 64;

// ---------------- workspace layout (floats) ----------------
constexpr int OFF_HYP_S = 0;                               // 4096*64
constexpr int OFF_HYP_G = OFF_HYP_S + N_SPECIES * EMB;     // 60*64
constexpr int OFF_S2    = OFF_HYP_G + N_GENUS * EMB;       // 4096
constexpr int OFF_G2    = OFF_S2 + N_SPECIES;              // 64 (60 used)
constexpr int OFF_X2    = OFF_G2 + 64;                     // 1024
constexpr int OFF_CNT   = OFF_X2 + NB;                     // 1 int: #present species (= nvs)
constexpr int OFF_NVG   = OFF_CNT + 1;                     // 1 float: #valid genera
constexpr int OFF_SPART = OFF_CNT + 2;                     // 1024 float2 (pos,neg) per species-dist block
constexpr int OFF_GPART = OFF_SPART + 2 * NB;              // 1024 float2 (pos,neg) per present-list item
constexpr int OFF_LIST  = OFF_GPART + 2 * NB;              // 1024 ints (compact present list)

// ---------------- helpers ----------------
__device__ __forceinline__ float wave_sum(float v) {
    #pragma unroll
    for (int off = 32; off; off >>= 1) v += __shfl_xor(v, off);
    return v;
}

// Given dot_ay = a.y (a = -x), a2 = ||a||^2, y2 = ||y||^2:
//   d      = 2/sqrt(c) * atanh(arg),  arg = clip(sqrt(c)*||num||/|den|, 0, 1-1e-5)
//   sp_neg = softplus(-d)
// Trick: u = (1-arg)/(1+arg) in (0,1];  L = log2(u)
//   d = -(ln2/sqrt(c)) * L,   exp(-d) = u^(1/sqrt(c)) = exp2(L/sqrt(c))
// All transcendentals native HW ops — tolerance is ~2% relative.
__device__ __forceinline__ void pair_terms(float dot_ay, float a2, float y2,
                                           float& d, float& sp_neg) {
    float ca   = fmaf(2.0f * C_CURV, dot_ay, fmaf(C_CURV, y2, 1.0f));
    float cy   = fmaf(-C_CURV, a2, 1.0f);
    float num2 = fmaf(ca * ca, a2, fmaf(2.0f * ca * cy, dot_ay, cy * cy * y2));
    float den  = fmaf(2.0f * C_CURV, dot_ay, fmaf(C_CURV * C_CURV, a2 * y2, 1.0f));
    float arg  = SQRT_C * __builtin_amdgcn_sqrtf(fmaxf(num2, 0.0f))
                        * __builtin_amdgcn_rcpf(fmaxf(fabsf(den), 1e-15f));
    arg = fminf(arg, 1.0f - 1e-5f);
    float u = (1.0f - arg) * __builtin_amdgcn_rcpf(1.0f + arg);
    float L = __builtin_amdgcn_logf(u);                    // log2(u) <= 0
    d       = -2.19201176f * L;                            // (ln2/sqrt(c)) * (-L)
    float e = __builtin_amdgcn_exp2f(3.16227766f * L);     // exp(-d)
    sp_neg  = 0.69314718f * __builtin_amdgcn_logf(1.0f + e);
}

// ---------------- K1: project rows onto Poincare ball + norms^2 ----------------
__global__ __launch_bounds__(256) void k_project(
    const float* __restrict__ X, const float* __restrict__ gp,
    const float* __restrict__ sp, float* __restrict__ ws)
{
    int wave = (blockIdx.x * blockDim.x + threadIdx.x) >> 6;
    int lane = threadIdx.x & 63;
    if (wave >= N_SPECIES + N_GENUS + NB) return;

    float v;
    if (wave < N_SPECIES)                 v = sp[wave * EMB + lane];
    else if (wave < N_SPECIES + N_GENUS)  v = gp[(wave - N_SPECIES) * EMB + lane];
    else                                  v = X[(wave - N_SPECIES - N_GENUS) * EMB + lane];

    float ss = wave_sum(v * v);
    if (wave >= N_SPECIES + N_GENUS) {          // X rows: just ||x||^2
        if (lane == 0) ws[OFF_X2 + (wave - N_SPECIES - N_GENUS)] = ss;
        return;
    }

    float n  = fmaxf(sqrtf(ss), 1e-5f);
    v *= fminf(1.0f, 2.3f / n);
    float n2 = fminf(n, 2.3f);
    float fac = tanhf(SQRT_C * n2) / (SQRT_C * n2);
    float y = fac * v;
    float ss2 = wave_sum(y * y);
    float yn = fmaxf(sqrtf(ss2), 1e-5f);
    const float maxnorm = (1.0f - 1e-3f) / SQRT_C;
    if (yn > maxnorm) {                         // wave-uniform branch
        y *= maxnorm / yn;
        ss2 = wave_sum(y * y);
    }
    if (wave < N_SPECIES) {
        ws[OFF_HYP_S + wave * EMB + lane] = y;
        if (lane == 0) ws[OFF_S2 + wave] = ss2;
    } else {
        int g = wave - N_SPECIES;
        ws[OFF_HYP_G + g * EMB + lane] = y;
        if (lane == 0) ws[OFF_G2 + g] = ss2;
    }
}

// ---------------- K2: present mask -> compact list, counts (LDS atomics only) ----------------
__global__ __launch_bounds__(1024) void k_masks(
    const int* __restrict__ Ts, const int* __restrict__ s2g, float* __restrict__ ws)
{
    __shared__ unsigned char pres[N_SPECIES];
    __shared__ unsigned char gm[64];
    __shared__ int scnt, gcnt;
    int t = threadIdx.x;
    int* wsI = (int*)ws;
    for (int s = t; s < N_SPECIES; s += 1024) pres[s] = 0;
    if (t < 64) gm[t] = 0;
    if (t == 0) { scnt = 0; gcnt = 0; }
    __syncthreads();
    pres[Ts[t]] = 1;                 // t in [0,1024)
    __syncthreads();
    for (int s = t; s < N_SPECIES; s += 1024) {
        if (pres[s]) {
            gm[s2g[s]] = 1;
            int idx = atomicAdd(&scnt, 1);       // LDS atomic: per-CU, fast
            wsI[OFF_LIST + idx] = s;
        }
    }
    __syncthreads();
    if (t < N_GENUS && gm[t]) atomicAdd(&gcnt, 1);
    __syncthreads();
    if (t == 0) { wsI[OFF_CNT] = scnt; ws[OFF_NVG] = (float)gcnt; }
}

// ---------------- K3: species-level pair distances (B x S), per-block partials ----------------
#define LDPAD 68   // 17 float4s: rows 16B-aligned, row stride = 4 banks
__global__ __launch_bounds__(256) void k_species_dist(
    const float* __restrict__ X, const int* __restrict__ Ts, float* __restrict__ ws)
{
    __shared__ float xs[64][LDPAD];
    __shared__ float ssm[64][LDPAD];
    __shared__ float x2s[64], s2s[64];
    __shared__ int   tss[64];
    __shared__ float red[8];

    int t = threadIdx.x;
    int sBase = blockIdx.x * 64;
    int bBase = blockIdx.y * 64;

    #pragma unroll
    for (int r = 0; r < 16; ++r) {
        int flat = r * 256 + t;          // 0..4095
        int row = flat >> 6, k = flat & 63;
        xs[row][k]  = X[(bBase + row) * EMB + k];
        ssm[row][k] = ws[OFF_HYP_S + (sBase + row) * EMB + k];
    }
    if (t < 64) {
        x2s[t] = ws[OFF_X2 + bBase + t];
        s2s[t] = ws[OFF_S2 + sBase + t];
        tss[t] = Ts[bBase + t];
    }
    __syncthreads();

    int sx = t & 15, sy = t >> 4;
    float acc[4][4];
    #pragma unroll
    for (int i = 0; i < 4; ++i)
        #pragma unroll
        for (int j = 0; j < 4; ++j) acc[i][j] = 0.0f;

    #pragma unroll
    for (int k = 0; k < EMB; k += 4) {
        float4 av[4], bv[4];
        #pragma unroll
        for (int i = 0; i < 4; ++i)
            av[i] = *reinterpret_cast<const float4*>(&xs[sy + 16 * i][k]);
        #pragma unroll
        for (int j = 0; j < 4; ++j)
            bv[j] = *reinterpret_cast<const float4*>(&ssm[sx + 16 * j][k]);
        #pragma unroll
        for (int i = 0; i < 4; ++i)
            #pragma unroll
            for (int j = 0; j < 4; ++j)
                acc[i][j] = fmaf(av[i].x, bv[j].x, fmaf(av[i].y, bv[j].y,
                            fmaf(av[i].z, bv[j].z, fmaf(av[i].w, bv[j].w, acc[i][j]))));
    }

    float pos = 0.0f, neg = 0.0f;
    #pragma unroll
    for (int i = 0; i < 4; ++i) {
        int bl = sy + 16 * i;
        float a2 = x2s[bl];
        int target = tss[bl];
        #pragma unroll
        for (int j = 0; j < 4; ++j) {
            int sl = sx + 16 * j;
            float d, l;
            pair_terms(-acc[i][j], a2, s2s[sl], d, l);
            if (target == sBase + sl) pos += d + l;        // softplus(d) = d + softplus(-d)
            else                      neg += l;
        }
    }
    pos = wave_sum(pos);
    neg = wave_sum(neg);
    int w = t >> 6;
    if ((t & 63) == 0) { red[2 * w] = pos; red[2 * w + 1] = neg; }
    __syncthreads();
    if (t == 0) {
        float2 out;
        out.x = red[0] + red[2] + red[4] + red[6];
        out.y = red[1] + red[3] + red[5] + red[7];
        int blk = blockIdx.y * gridDim.x + blockIdx.x;     // 0..1023
        reinterpret_cast<float2*>(ws + OFF_SPART)[blk] = out;  // plain store, no atomics
    }
}

// ---------------- K4: genus-level distances, compacted present species ----------------
// 256 blocks x 256 threads; wave w of block b handles present-list item b*4+w.
// Every item slot (0..1023) gets its partial written (zeros if item >= cnt).
__global__ __launch_bounds__(256) void k_genus_dist(
    const int* __restrict__ s2g, float* __restrict__ ws)
{
    __shared__ float hgt[EMB][61];   // transposed genus tile [k][g], odd stride
    __shared__ float hs[4][EMB];
    __shared__ float g2s[64];

    int t = threadIdx.x;
    const int* wsI = (const int*)ws;
    int cnt  = wsI[OFF_CNT];
    int w    = t >> 6, lane = t & 63;
    int item = blockIdx.x * 4 + w;
    int s    = (item < cnt) ? wsI[OFF_LIST + item] : -1;

    for (int idx = t; idx < N_GENUS * EMB; idx += 256)
        hgt[idx & 63][idx >> 6] = ws[OFF_HYP_G + idx];
    if (t < 64) g2s[t] = (t < N_GENUS) ? ws[OFF_G2 + t] : 0.0f;
    if (s >= 0) hs[w][lane] = ws[OFF_HYP_S + s * EMB + lane];
    __syncthreads();

    float pos = 0.0f, neg = 0.0f;
    if (s >= 0 && lane < N_GENUS) {
        float dot = 0.0f;
        #pragma unroll
        for (int k = 0; k < EMB; ++k) dot = fmaf(hs[w][k], hgt[k][lane], dot);
        float d, l;
        pair_terms(-dot, ws[OFF_S2 + s], g2s[lane], d, l);
        if (s2g[s] == lane) pos = d + l;
        else                neg = l;
    }
    pos = wave_sum(pos);
    neg = wave_sum(neg);
    if (lane == 0) {
        float2 out; out.x = pos; out.y = neg;
        reinterpret_cast<float2*>(ws + OFF_GPART)[item] = out; // plain store
    }
}

// ---------------- K5: reduce partials + combine ----------------
__global__ __launch_bounds__(256) void k_final(const float* __restrict__ ws, float* __restrict__ out)
{
    __shared__ float red[16];
    int t = threadIdx.x;
    const float2* sp = reinterpret_cast<const float2*>(ws + OFF_SPART);
    const float2* gp = reinterpret_cast<const float2*>(ws + OFF_GPART);
    float ps = 0.0f, ns = 0.0f, pg = 0.0f, ng = 0.0f;
    for (int i = t; i < NB; i += 256) {
        float2 a = sp[i]; ps += a.x; ns += a.y;
        float2 b = gp[i]; pg += b.x; ng += b.y;
    }
    ps = wave_sum(ps); ns = wave_sum(ns); pg = wave_sum(pg); ng = wave_sum(ng);
    int w = t >> 6;
    if ((t & 63) == 0) { red[4*w] = ps; red[4*w+1] = ns; red[4*w+2] = pg; red[4*w+3] = ng; }
    __syncthreads();
    if (t == 0) {
        ps = red[0] + red[4] + red[8]  + red[12];
        ns = red[1] + red[5] + red[9]  + red[13];
        pg = red[2] + red[6] + red[10] + red[14];
        ng = red[3] + red[7] + red[11] + red[15];
        const int* wsI = (const int*)ws;
        float nvs = fmaxf((float)wsI[OFF_CNT], 1.0f);
        float nvg = fmaxf(ws[OFF_NVG], 1.0f);
        out[0] = ps / nvs + ns / (float)N_SPECIES + pg / nvg + ng / (float)N_GENUS;
    }
}

extern "C" void kernel_launch(void* const* d_in, const int* in_sizes, int n_in,
                              void* d_out, int out_size, void* d_ws, size_t ws_size,
                              hipStream_t stream) {
    const float* X   = (const float*)d_in[0];
    const int*   Ts  = (const int*)d_in[1];
    // d_in[2] = T_genus: unused by the reference loss
    const int*   s2g = (const int*)d_in[3];
    const float* gp  = (const float*)d_in[4];
    const float* sp  = (const float*)d_in[5];
    float* ws  = (float*)d_ws;
    float* out = (float*)d_out;

    k_project<<<(N_SPECIES + N_GENUS + NB) / 4, 256, 0, stream>>>(X, gp, sp, ws);
    k_masks<<<1, 1024, 0, stream>>>(Ts, s2g, ws);
    dim3 g3(N_SPECIES / 64, NB / 64);   // (64, 16)
    k_species_dist<<<g3, 256, 0, stream>>>(X, Ts, ws);
    k_genus_dist<<<256, 256, 0, stream>>>(s2g, ws);
    k_final<<<1, 256, 0, stream>>>(ws, out);
}

// Round 4
// 81.969 us; speedup vs baseline: 3.6965x; 1.1310x over previous
//
#include <hip/hip_runtime.h>
#include <math.h>

// ---------------- problem constants ----------------
constexpr float C_CURV = 0.1f;
constexpr float SQRT_C = 0.31622776601683794f;        // sqrt(0.1)

constexpr int N_GENUS   = 60;
constexpr int N_SPECIES = 4096;
constexpr int NB        = 1024;   // batch
constexpr int EMB       = 64;

// ---------------- workspace layout (floats) ----------------
constexpr int OFF_HYP_S = 0;                               // 4096*64 fp32 (genus branch reads)
constexpr int OFF_HYP_G = OFF_HYP_S + N_SPECIES * EMB;     // 60*64
constexpr int OFF_S2    = OFF_HYP_G + N_GENUS * EMB;       // 4096
constexpr int OFF_G2    = OFF_S2 + N_SPECIES;              // 64 (60 used)
constexpr int OFF_X2    = OFF_G2 + 64;                     // 1024
constexpr int OFF_CNT   = OFF_X2 + NB;                     // 1 int: #present species (= nvs)
constexpr int OFF_NVG   = OFF_CNT + 1;                     // 1 float: #valid genera
constexpr int OFF_SPART = OFF_CNT + 2;                     // 1024 float2 partials (species blocks)
constexpr int OFF_GPART = OFF_SPART + 2 * NB;              // 1024 float2 partials (genus items)
constexpr int OFF_LIST  = OFF_GPART + 2 * NB;              // 1024 ints compact present list
// bf16 copies, padded row stride 72 (16B-aligned rows; stride = 9x16B)
constexpr int OFF_XBF   = ((OFF_LIST + NB + 3) / 4) * 4;   // 1024*72 ushort = 36864 floats
constexpr int OFF_SBF   = OFF_XBF + NB * 72 / 2;           // 4096*72 ushort = 147456 floats
constexpr int BFSTRIDE  = 72;                              // ushorts per row

typedef short  bf16x8 __attribute__((ext_vector_type(8)));
typedef float  f32x4  __attribute__((ext_vector_type(4)));

// ---------------- helpers ----------------
__device__ __forceinline__ float wave_sum(float v) {
    #pragma unroll
    for (int off = 32; off; off >>= 1) v += __shfl_xor(v, off);
    return v;
}

__device__ __forceinline__ unsigned short f2bf(float f) {   // RNE f32 -> bf16
    unsigned int u = __builtin_bit_cast(unsigned int, f);
    u += 0x7FFFu + ((u >> 16) & 1u);
    return (unsigned short)(u >> 16);
}

// d = 2/sqrt(c)*atanh(arg); sp_neg = softplus(-d). u=(1-arg)/(1+arg), L=log2(u):
// d = -(ln2/sqrt(c))*L, exp(-d) = exp2(L/sqrt(c)). Native HW transcendentals only.
__device__ __forceinline__ void pair_terms(float dot_ay, float a2, float y2,
                                           float& d, float& sp_neg) {
    float ca   = fmaf(2.0f * C_CURV, dot_ay, fmaf(C_CURV, y2, 1.0f));
    float cy   = fmaf(-C_CURV, a2, 1.0f);
    float num2 = fmaf(ca * ca, a2, fmaf(2.0f * ca * cy, dot_ay, cy * cy * y2));
    float den  = fmaf(2.0f * C_CURV, dot_ay, fmaf(C_CURV * C_CURV, a2 * y2, 1.0f));
    float arg  = SQRT_C * __builtin_amdgcn_sqrtf(fmaxf(num2, 0.0f))
                        * __builtin_amdgcn_rcpf(fmaxf(fabsf(den), 1e-15f));
    arg = fminf(arg, 1.0f - 1e-5f);
    float u = (1.0f - arg) * __builtin_amdgcn_rcpf(1.0f + arg);
    float L = __builtin_amdgcn_logf(u);                    // log2(u) <= 0
    d       = -2.19201176f * L;
    float e = __builtin_amdgcn_exp2f(3.16227766f * L);     // exp(-d)
    sp_neg  = 0.69314718f * __builtin_amdgcn_logf(1.0f + e);
}

// ---------------- K1: fused prep ----------------
// blocks 0..1294: projection waves (species 0..4095, genus 4096..4155, X 4156..5179)
// block 1295: present mask -> compact list + counts (LDS atomics only)
__global__ __launch_bounds__(256) void k_prep(
    const float* __restrict__ X, const int* __restrict__ Ts,
    const int* __restrict__ s2g, const float* __restrict__ gp,
    const float* __restrict__ sp, float* __restrict__ ws)
{
    __shared__ unsigned char pres[N_SPECIES];
    __shared__ unsigned char gm[64];
    __shared__ int scnt, gcnt;

    int t = threadIdx.x;
    unsigned short* xbf = (unsigned short*)(ws + OFF_XBF);
    unsigned short* sbf = (unsigned short*)(ws + OFF_SBF);

    if (blockIdx.x == 1295) {           // ---- mask block ----
        int* wsI = (int*)ws;
        for (int s = t; s < N_SPECIES; s += 256) pres[s] = 0;
        if (t < 64) gm[t] = 0;
        if (t == 0) { scnt = 0; gcnt = 0; }
        __syncthreads();
        #pragma unroll
        for (int i = 0; i < 4; ++i) pres[Ts[t + 256 * i]] = 1;
        __syncthreads();
        for (int s = t; s < N_SPECIES; s += 256) {
            if (pres[s]) {
                gm[s2g[s]] = 1;
                int idx = atomicAdd(&scnt, 1);
                wsI[OFF_LIST + idx] = s;
            }
        }
        __syncthreads();
        if (t < N_GENUS && gm[t]) atomicAdd(&gcnt, 1);
        __syncthreads();
        if (t == 0) { wsI[OFF_CNT] = scnt; ws[OFF_NVG] = (float)gcnt; }
        return;
    }

    // ---- projection waves ----
    int wave = blockIdx.x * 4 + (t >> 6);
    int lane = t & 63;

    float v;
    if (wave < N_SPECIES)                 v = sp[wave * EMB + lane];
    else if (wave < N_SPECIES + N_GENUS)  v = gp[(wave - N_SPECIES) * EMB + lane];
    else                                  v = X[(wave - N_SPECIES - N_GENUS) * EMB + lane];

    float ss = wave_sum(v * v);
    if (wave >= N_SPECIES + N_GENUS) {          // X rows: ||x||^2 + bf16 copy
        int row = wave - N_SPECIES - N_GENUS;
        xbf[row * BFSTRIDE + lane] = f2bf(v);
        if (lane == 0) ws[OFF_X2 + row] = ss;
        return;
    }

    float n  = fmaxf(__builtin_amdgcn_sqrtf(ss), 1e-5f);
    v *= fminf(1.0f, 2.3f * __builtin_amdgcn_rcpf(n));
    float n2 = fminf(n, 2.3f);
    float z  = SQRT_C * n2;
    float ez = __builtin_amdgcn_exp2f(-2.88539008f * z);   // exp(-2z)
    float th = (1.0f - ez) * __builtin_amdgcn_rcpf(1.0f + ez);
    float fac = th * __builtin_amdgcn_rcpf(z);
    float y = fac * v;
    float ss2 = wave_sum(y * y);
    float yn = fmaxf(__builtin_amdgcn_sqrtf(ss2), 1e-5f);
    const float maxnorm = (1.0f - 1e-3f) / SQRT_C;
    if (yn > maxnorm) {                         // wave-uniform
        y *= maxnorm * __builtin_amdgcn_rcpf(yn);
        ss2 = maxnorm * maxnorm;
    }
    if (wave < N_SPECIES) {
        ws[OFF_HYP_S + wave * EMB + lane] = y;
        sbf[wave * BFSTRIDE + lane] = f2bf(y);
        if (lane == 0) ws[OFF_S2 + wave] = ss2;
    } else {
        int g = wave - N_SPECIES;
        ws[OFF_HYP_G + g * EMB + lane] = y;
        if (lane == 0) ws[OFF_G2 + g] = ss2;
    }
}

// ---------------- K2: fused distance kernel ----------------
// blocks 0..1023: species 64x64 tile via MFMA bf16. blocks 1024..1279: genus (4 items each)
union SharedU {
    struct {
        uint4 xs[576];        // 64 rows x 72 bf16 (padded)
        uint4 ss[576];
        float x2s[64], s2s[64];
        int   tss[64];
        float red[8];
    } sp;
    struct {
        float hgt[EMB][61];   // transposed genus tile
        float hs[4][EMB];
        float g2s[64];
    } ge;
};

__global__ __launch_bounds__(256) void k_dist(
    const int* __restrict__ Ts, const int* __restrict__ s2g, float* __restrict__ ws)
{
    __shared__ SharedU sh;
    int t = threadIdx.x;
    int bx = blockIdx.x;

    if (bx < 1024) {                     // ---------- species branch ----------
        int sBase = (bx & 63) * 64;
        int bBase = (bx >> 6) * 64;
        const unsigned short* xbf = (const unsigned short*)(ws + OFF_XBF);
        const unsigned short* sbf = (const unsigned short*)(ws + OFF_SBF);
        const uint4* srcx = (const uint4*)(xbf + bBase * BFSTRIDE);
        const uint4* srcs = (const uint4*)(sbf + sBase * BFSTRIDE);
        for (int i = t; i < 576; i += 256) { sh.sp.xs[i] = srcx[i]; sh.sp.ss[i] = srcs[i]; }
        if (t < 64) {
            sh.sp.x2s[t] = ws[OFF_X2 + bBase + t];
            sh.sp.s2s[t] = ws[OFF_S2 + sBase + t];
            sh.sp.tss[t] = Ts[bBase + t];
        }
        __syncthreads();

        int lane = t & 63, w = t >> 6;
        int nloc = lane & 15, quad = lane >> 4;
        const unsigned short* xs = (const unsigned short*)sh.sp.xs;
        const unsigned short* sb = (const unsigned short*)sh.sp.ss;

        f32x4 acc[4] = {{0.f,0.f,0.f,0.f},{0.f,0.f,0.f,0.f},{0.f,0.f,0.f,0.f},{0.f,0.f,0.f,0.f}};
        #pragma unroll
        for (int k0 = 0; k0 < EMB; k0 += 32) {
            // A frag: rows 16w..16w+15 (m=lane&15), k = k0 + quad*8 + j
            bf16x8 a = *(const bf16x8*)(xs + (16 * w + nloc) * BFSTRIDE + k0 + quad * 8);
            #pragma unroll
            for (int jt = 0; jt < 4; ++jt) {
                bf16x8 b = *(const bf16x8*)(sb + (16 * jt + nloc) * BFSTRIDE + k0 + quad * 8);
                acc[jt] = __builtin_amdgcn_mfma_f32_16x16x32_bf16(a, b, acc[jt], 0, 0, 0);
            }
        }

        // C/D layout: col = lane&15, row = quad*4 + reg
        float pos = 0.0f, neg = 0.0f;
        #pragma unroll
        for (int jt = 0; jt < 4; ++jt) {
            int sl = 16 * jt + nloc;
            float y2 = sh.sp.s2s[sl];
            #pragma unroll
            for (int r = 0; r < 4; ++r) {
                int m = 16 * w + quad * 4 + r;
                float d, lterm;
                pair_terms(-acc[jt][r], sh.sp.x2s[m], y2, d, lterm);
                if (sh.sp.tss[m] == sBase + sl) pos += d + lterm;   // softplus(d)=d+softplus(-d)
                else                            neg += lterm;
            }
        }
        pos = wave_sum(pos);
        neg = wave_sum(neg);
        if (lane == 0) { sh.sp.red[2 * w] = pos; sh.sp.red[2 * w + 1] = neg; }
        __syncthreads();
        if (t == 0) {
            float2 o;
            o.x = sh.sp.red[0] + sh.sp.red[2] + sh.sp.red[4] + sh.sp.red[6];
            o.y = sh.sp.red[1] + sh.sp.red[3] + sh.sp.red[5] + sh.sp.red[7];
            reinterpret_cast<float2*>(ws + OFF_SPART)[bx] = o;
        }
    } else {                             // ---------- genus branch ----------
        const int* wsI = (const int*)ws;
        int cnt  = wsI[OFF_CNT];
        int w    = t >> 6, lane = t & 63;
        int item = (bx - 1024) * 4 + w;
        int s    = (item < cnt) ? wsI[OFF_LIST + item] : -1;

        for (int idx = t; idx < N_GENUS * EMB; idx += 256)
            sh.ge.hgt[idx & 63][idx >> 6] = ws[OFF_HYP_G + idx];
        if (t < 64) sh.ge.g2s[t] = (t < N_GENUS) ? ws[OFF_G2 + t] : 0.0f;
        if (s >= 0) sh.ge.hs[w][lane] = ws[OFF_HYP_S + s * EMB + lane];
        __syncthreads();

        float pos = 0.0f, neg = 0.0f;
        if (s >= 0 && lane < N_GENUS) {
            float dot = 0.0f;
            #pragma unroll
            for (int k = 0; k < EMB; ++k) dot = fmaf(sh.ge.hs[w][k], sh.ge.hgt[k][lane], dot);
            float d, lterm;
            pair_terms(-dot, ws[OFF_S2 + s], sh.ge.g2s[lane], d, lterm);
            if (s2g[s] == lane) pos = d + lterm;
            else                neg = lterm;
        }
        pos = wave_sum(pos);
        neg = wave_sum(neg);
        if (lane == 0) {
            float2 o; o.x = pos; o.y = neg;
            reinterpret_cast<float2*>(ws + OFF_GPART)[item] = o;
        }
    }
}

// ---------------- K3: reduce partials + combine ----------------
__global__ __launch_bounds__(256) void k_final(const float* __restrict__ ws, float* __restrict__ out)
{
    __shared__ float red[16];
    int t = threadIdx.x;
    const float2* spp = reinterpret_cast<const float2*>(ws + OFF_SPART);
    const float2* gpp = reinterpret_cast<const float2*>(ws + OFF_GPART);
    float ps = 0.0f, ns = 0.0f, pg = 0.0f, ng = 0.0f;
    for (int i = t; i < NB; i += 256) {
        float2 a = spp[i]; ps += a.x; ns += a.y;
        float2 b = gpp[i]; pg += b.x; ng += b.y;
    }
    ps = wave_sum(ps); ns = wave_sum(ns); pg = wave_sum(pg); ng = wave_sum(ng);
    int w = t >> 6;
    if ((t & 63) == 0) { red[4*w] = ps; red[4*w+1] = ns; red[4*w+2] = pg; red[4*w+3] = ng; }
    __syncthreads();
    if (t == 0) {
        ps = red[0] + red[4] + red[8]  + red[12];
        ns = red[1] + red[5] + red[9]  + red[13];
        pg = red[2] + red[6] + red[10] + red[14];
        ng = red[3] + red[7] + red[11] + red[15];
        const int* wsI = (const int*)ws;
        float nvs = fmaxf((float)wsI[OFF_CNT], 1.0f);
        float nvg = fmaxf(ws[OFF_NVG], 1.0f);
        out[0] = ps / nvs + ns / (float)N_SPECIES + pg / nvg + ng / (float)N_GENUS;
    }
}

extern "C" void kernel_launch(void* const* d_in, const int* in_sizes, int n_in,
                              void* d_out, int out_size, void* d_ws, size_t ws_size,
                              hipStream_t stream) {
    const float* X   = (const float*)d_in[0];
    const int*   Ts  = (const int*)d_in[1];
    // d_in[2] = T_genus: unused by the reference loss
    const int*   s2g = (const int*)d_in[3];
    const float* gp  = (const float*)d_in[4];
    const float* sp  = (const float*)d_in[5];
    float* ws  = (float*)d_ws;
    float* out = (float*)d_out;

    k_prep<<<1296, 256, 0, stream>>>(X, Ts, s2g, gp, sp, ws);
    k_dist<<<1280, 256, 0, stream>>>(Ts, s2g, ws);
    k_final<<<1, 256, 0, stream>>>(ws, out);
}